// Round 4
// baseline (400.178 us; speedup 1.0000x reference)
//
#include <hip/hip_runtime.h>
#include <stdint.h>

#define S_LEN 2048
#define HID   2048
#define NHEAD 16
#define HDIM  128
#define LDQK  4096   // row stride of mixed Q|K buffer

typedef unsigned short ushort_t;
using bf16x8 = __attribute__((ext_vector_type(8))) short;
using f32x4  = __attribute__((ext_vector_type(4))) float;

__device__ __forceinline__ float bf2f(ushort_t u) {
  union { uint32_t i; float f; } v; v.i = ((uint32_t)u) << 16; return v.f;
}
__device__ __forceinline__ ushort_t f2bf(float f) {
  union { float f; uint32_t i; } v; v.f = f;
  uint32_t r = v.i + 0x7fffu + ((v.i >> 16) & 1u);
  return (ushort_t)(r >> 16);
}
__device__ __forceinline__ void store_val(ushort_t* C, size_t idx, float v) { C[idx] = f2bf(v); }
__device__ __forceinline__ void store_val(float* C, size_t idx, float v) { C[idx] = v; }

__device__ __forceinline__ bf16x8 load8(const ushort_t* p) { return *(const bf16x8*)p; }
__device__ __forceinline__ bf16x8 load8(const float* p) {
  float4 a = *(const float4*)p, b = *(const float4*)(p + 4);
  ushort_t o[8] = { f2bf(a.x), f2bf(a.y), f2bf(a.z), f2bf(a.w),
                    f2bf(b.x), f2bf(b.y), f2bf(b.z), f2bf(b.w) };
  return *(const bf16x8*)o;
}

// async global->LDS, 16B per lane, LDS dest = wave-uniform base + lane*16
__device__ __forceinline__ void gl_lds16(const ushort_t* g, short* l) {
  __builtin_amdgcn_global_load_lds((const __attribute__((address_space(1))) void*)g,
                                   (__attribute__((address_space(3))) void*)l, 16, 0, 0);
}

// ---------------- fp32 -> bf16 conversion ----------------
__global__ __launch_bounds__(256) void cvt_f32_bf16(const float* __restrict__ src,
                                                    ushort_t* __restrict__ dst, int n8) {
  int i = blockIdx.x * 256 + threadIdx.x;
  if (i >= n8) return;
  float4 a = ((const float4*)src)[i * 2], b = ((const float4*)src)[i * 2 + 1];
  ushort_t o[8] = { f2bf(a.x), f2bf(a.y), f2bf(a.z), f2bf(a.w),
                    f2bf(b.x), f2bf(b.y), f2bf(b.z), f2bf(b.w) };
  ((uint4*)dst)[i] = *(const uint4*)o;
}

// ---------------- LayerNorm: fp32 in, bf16 out ----------------
__global__ __launch_bounds__(256) void ln_kernel(const float* __restrict__ x,
                                                 const float* __restrict__ w,
                                                 const float* __restrict__ b,
                                                 ushort_t* __restrict__ y) {
  const int row = blockIdx.x;
  const int t = threadIdx.x;
  const float4* xr = (const float4*)(x + (size_t)row * HID);
  float4 v0 = xr[t], v1 = xr[t + 256];
  float s  = v0.x + v0.y + v0.z + v0.w + v1.x + v1.y + v1.z + v1.w;
  float ss = v0.x*v0.x + v0.y*v0.y + v0.z*v0.z + v0.w*v0.w
           + v1.x*v1.x + v1.y*v1.y + v1.z*v1.z + v1.w*v1.w;
#pragma unroll
  for (int off = 32; off > 0; off >>= 1) { s += __shfl_xor(s, off, 64); ss += __shfl_xor(ss, off, 64); }
  __shared__ float red[8];
  const int wv = t >> 6;
  if ((t & 63) == 0) { red[wv * 2] = s; red[wv * 2 + 1] = ss; }
  __syncthreads();
  s  = red[0] + red[2] + red[4] + red[6];
  ss = red[1] + red[3] + red[5] + red[7];
  const float mu   = s * (1.f / HID);
  const float var  = ss * (1.f / HID) - mu * mu;
  const float rstd = rsqrtf(var + 1e-5f);
  const float4* wr = (const float4*)w;
  const float4* br = (const float4*)b;
  float4 w0 = wr[t], w1 = wr[t + 256];
  float4 b0 = br[t], b1 = br[t + 256];
  ushort_t* yr = y + (size_t)row * HID;
  ushort_t o0[4] = { f2bf((v0.x - mu) * rstd * w0.x + b0.x), f2bf((v0.y - mu) * rstd * w0.y + b0.y),
                     f2bf((v0.z - mu) * rstd * w0.z + b0.z), f2bf((v0.w - mu) * rstd * w0.w + b0.w) };
  ushort_t o1[4] = { f2bf((v1.x - mu) * rstd * w1.x + b1.x), f2bf((v1.y - mu) * rstd * w1.y + b1.y),
                     f2bf((v1.z - mu) * rstd * w1.z + b1.z), f2bf((v1.w - mu) * rstd * w1.w + b1.w) };
  *(uint2*)(&yr[4 * t])         = *(const uint2*)o0;
  *(uint2*)(&yr[4 * (t + 256)]) = *(const uint2*)o1;
}

// ---- m97-style GEMM (bf16 A and B): global_load_lds staging, unpadded 128x32 tiles ----
template <bool SPLIT, typename OUT_T>
__global__ __launch_bounds__(256) void gemm_lds(const ushort_t* __restrict__ A,
                                                const ushort_t* __restrict__ B,
                                                const float* __restrict__ bias,
                                                OUT_T* __restrict__ C,
                                                ushort_t* __restrict__ VTg,
                                                int M, int N, int K, int ldc) {
  __shared__ __align__(16) short As[128 * 32];
  __shared__ __align__(16) short Bs[128 * 32];
  const int mb = blockIdx.x * 128, nb = blockIdx.y * 128;
  const int t = threadIdx.x, wave = t >> 6, lane = t & 63;
  const int wm = (wave >> 1) * 64, wn = (wave & 1) * 64;
  const int lrow = lane & 15, quad = lane >> 4;
  const int srow = lane >> 2, scol = (lane & 3) * 8;  // staging: 4 lanes per 32-elem row
  const f32x4 vzero = {0.f, 0.f, 0.f, 0.f};

  f32x4 acc[4][4];
#pragma unroll
  for (int i = 0; i < 4; i++)
#pragma unroll
    for (int j = 0; j < 4; j++) acc[i][j] = vzero;

  for (int k0 = 0; k0 < K; k0 += 32) {
    __syncthreads();
#pragma unroll
    for (int kb = 0; kb < 2; kb++) {
      const int c = wave * 2 + kb;          // chunk 0..7, 16 rows each
      const int row = c * 16 + srow;
      gl_lds16(&A[(size_t)(mb + row) * K + k0 + scol], &As[c * 512]);
      gl_lds16(&B[(size_t)(nb + row) * K + k0 + scol], &Bs[c * 512]);
    }
    __syncthreads();
    bf16x8 af[4], bfg[4];
#pragma unroll
    for (int mi = 0; mi < 4; mi++) af[mi] = *(const bf16x8*)(&As[(wm + mi * 16 + lrow) * 32 + quad * 8]);
#pragma unroll
    for (int ni = 0; ni < 4; ni++) bfg[ni] = *(const bf16x8*)(&Bs[(wn + ni * 16 + lrow) * 32 + quad * 8]);
#pragma unroll
    for (int mi = 0; mi < 4; mi++)
#pragma unroll
      for (int ni = 0; ni < 4; ni++)
        acc[mi][ni] = __builtin_amdgcn_mfma_f32_16x16x32_bf16(af[mi], bfg[ni], acc[mi][ni], 0, 0, 0);
  }

#pragma unroll
  for (int mi = 0; mi < 4; mi++)
#pragma unroll
    for (int ni = 0; ni < 4; ni++) {
      const int col = nb + wn + ni * 16 + lrow;
      const float bv = bias[col];
      const int row0 = mb + wm + mi * 16 + quad * 4;
      if (SPLIT && col >= 4096) {
        ushort_t o4[4];
#pragma unroll
        for (int r = 0; r < 4; r++) o4[r] = f2bf(acc[mi][ni][r] + bv);
        *(uint2*)(&VTg[(size_t)(col - 4096) * S_LEN + row0]) = *(const uint2*)o4;
      } else {
#pragma unroll
        for (int r = 0; r < 4; r++)
          store_val(C, (size_t)(row0 + r) * ldc + col, acc[mi][ni][r] + bv);
      }
    }
}

// ---- fallback GEMM (fp32 B converted in-loop), for small-ws path ----
template <bool SPLIT, typename OUT_T, typename BT>
__global__ __launch_bounds__(256) void gemm_bt(const ushort_t* __restrict__ A,
                                               const BT* __restrict__ B,
                                               const float* __restrict__ bias,
                                               OUT_T* __restrict__ C,
                                               ushort_t* __restrict__ VTg,
                                               int M, int N, int K, int ldc) {
  __shared__ __align__(16) short As[128 * 40];
  __shared__ __align__(16) short Bs[128 * 40];
  const int mb = blockIdx.x * 128, nb = blockIdx.y * 128;
  const int t = threadIdx.x, wave = t >> 6, lane = t & 63;
  const int wm = (wave >> 1) * 64, wn = (wave & 1) * 64;
  const int lrow = lane & 15, quad = lane >> 4;
  const f32x4 vzero = {0.f, 0.f, 0.f, 0.f};
  f32x4 acc[4][4];
#pragma unroll
  for (int i = 0; i < 4; i++)
#pragma unroll
    for (int j = 0; j < 4; j++) acc[i][j] = vzero;
  for (int k0 = 0; k0 < K; k0 += 32) {
    __syncthreads();
#pragma unroll
    for (int i = 0; i < 2; i++) {
      int c = t + 256 * i;
      int r = c >> 2, kc = (c & 3) * 8;
      *(bf16x8*)(&As[r * 40 + kc]) = load8(&A[(size_t)(mb + r) * K + k0 + kc]);
      *(bf16x8*)(&Bs[r * 40 + kc]) = load8(&B[(size_t)(nb + r) * K + k0 + kc]);
    }
    __syncthreads();
    bf16x8 af[4], bfg[4];
#pragma unroll
    for (int mi = 0; mi < 4; mi++) af[mi] = *(const bf16x8*)(&As[(wm + mi * 16 + lrow) * 40 + quad * 8]);
#pragma unroll
    for (int ni = 0; ni < 4; ni++) bfg[ni] = *(const bf16x8*)(&Bs[(wn + ni * 16 + lrow) * 40 + quad * 8]);
#pragma unroll
    for (int mi = 0; mi < 4; mi++)
#pragma unroll
      for (int ni = 0; ni < 4; ni++)
        acc[mi][ni] = __builtin_amdgcn_mfma_f32_16x16x32_bf16(af[mi], bfg[ni], acc[mi][ni], 0, 0, 0);
  }
#pragma unroll
  for (int mi = 0; mi < 4; mi++)
#pragma unroll
    for (int ni = 0; ni < 4; ni++) {
      const int col = nb + wn + ni * 16 + lrow;
      const float bv = bias[col];
      const int row0 = mb + wm + mi * 16 + quad * 4;
      if (SPLIT && col >= 4096) {
        ushort_t o4[4];
#pragma unroll
        for (int r = 0; r < 4; r++) o4[r] = f2bf(acc[mi][ni][r] + bv);
        *(uint2*)(&VTg[(size_t)(col - 4096) * S_LEN + row0]) = *(const uint2*)o4;
      } else {
#pragma unroll
        for (int r = 0; r < 4; r++)
          store_val(C, (size_t)(row0 + r) * ldc + col, acc[mi][ni][r] + bv);
      }
    }
}

// ---------------- Causal flash attention: LPT work-stealing + register prefetch ----------------
__global__ __launch_bounds__(256) void attn_kernel(const ushort_t* __restrict__ mixedQK,
                                                   const ushort_t* __restrict__ vtg,
                                                   ushort_t* __restrict__ ctx,
                                                   int* __restrict__ ctr) {
  __shared__ int sItem;
  const int t = threadIdx.x;
  if (t == 0) sItem = atomicAdd(ctr, 1);   // device-scope; LPT: biggest jobs pop first
  __syncthreads();
  const int item = sItem;
  const int h = item & 15;
  const int qblk = 31 - (item >> 4);       // qblk 31 (32 tiles) first, 0 (1 tile) last

  const int wave = t >> 6, lane = t & 63;
  const int lrow = lane & 15, quad = lane >> 4;
  const int q0 = qblk * 64 + wave * 16;
  const float scale = 0.08838834764831845f;  // 1/sqrt(128)
  const float SHIFT = 8.0f;                  // fixed softmax shift

  __shared__ __align__(16) short Ks[64 * 136];   // [64 kv][128+8]
  __shared__ __align__(16) short VTs[128 * 72];  // [128 d][64+8]
  __shared__ __align__(16) short Ps[4][16 * 72]; // per-wave P (wave-local, no barrier)

  bf16x8 qf[4];
  {
    const ushort_t* Qb = mixedQK + (size_t)(q0 + lrow) * LDQK + h * HDIM;
#pragma unroll
    for (int c = 0; c < 4; c++) qf[c] = *(const bf16x8*)(Qb + c * 32 + quad * 8);
  }

  const f32x4 vzero = {0.f, 0.f, 0.f, 0.f};
  float lsum[4] = {0.f, 0.f, 0.f, 0.f};
  f32x4 acc[8];
#pragma unroll
  for (int d = 0; d < 8; d++) acc[d] = vzero;

  uint4 kreg[4], vreg[4];
  // prefetch tile 0
#pragma unroll
  for (int i = 0; i < 4; i++) {
    int c = t + 256 * i; int r = c >> 4, kc = (c & 15) * 8;
    kreg[i] = *(const uint4*)(&mixedQK[(size_t)r * LDQK + 2048 + h * HDIM + kc]);
  }
#pragma unroll
  for (int i = 0; i < 4; i++) {
    int c = t + 256 * i; int dd = c >> 3, j8 = (c & 7) * 8;
    vreg[i] = *(const uint4*)(&vtg[(size_t)(h * HDIM + dd) * S_LEN + j8]);
  }

  const int ntiles = qblk + 1;
  for (int tk = 0; tk < ntiles; ++tk) {
    const int kv0 = tk * 64;
    __syncthreads();   // prior tile's LDS reads complete
#pragma unroll
    for (int i = 0; i < 4; i++) {
      int c = t + 256 * i; int r = c >> 4, kc = (c & 15) * 8;
      *(uint4*)(&Ks[r * 136 + kc]) = kreg[i];
    }
#pragma unroll
    for (int i = 0; i < 4; i++) {
      int c = t + 256 * i; int dd = c >> 3, j8 = (c & 7) * 8;
      *(uint4*)(&VTs[dd * 72 + j8]) = vreg[i];
    }
    __syncthreads();   // staging visible

    // issue next tile's global loads now — latency hides behind compute below
    if (tk + 1 < ntiles) {
      const int nv0 = kv0 + 64;
#pragma unroll
      for (int i = 0; i < 4; i++) {
        int c = t + 256 * i; int r = c >> 4, kc = (c & 15) * 8;
        kreg[i] = *(const uint4*)(&mixedQK[(size_t)(nv0 + r) * LDQK + 2048 + h * HDIM + kc]);
      }
#pragma unroll
      for (int i = 0; i < 4; i++) {
        int c = t + 256 * i; int dd = c >> 3, j8 = (c & 7) * 8;
        vreg[i] = *(const uint4*)(&vtg[(size_t)(h * HDIM + dd) * S_LEN + nv0 + j8]);
      }
    }

    // S = Q K^T
    f32x4 sc[4];
#pragma unroll
    for (int ni = 0; ni < 4; ni++) sc[ni] = vzero;
#pragma unroll
    for (int ni = 0; ni < 4; ni++)
#pragma unroll
      for (int c = 0; c < 4; c++) {
        bf16x8 kf = *(const bf16x8*)(&Ks[(ni * 16 + lrow) * 136 + c * 32 + quad * 8]);
        sc[ni] = __builtin_amdgcn_mfma_f32_16x16x32_bf16(qf[c], kf, sc[ni], 0, 0, 0);
      }

    // fixed-shift softmax -> bf16 P (per-wave LDS; wave-internal lgkm ordering suffices)
    short* P = &Ps[wave][0];
#pragma unroll
    for (int r = 0; r < 4; r++) {
      const int row = q0 + quad * 4 + r;
#pragma unroll
      for (int ni = 0; ni < 4; ni++) {
        const int col = kv0 + ni * 16 + lrow;
        float p = (col > row) ? 0.f : __expf(sc[ni][r] * scale - SHIFT);
        lsum[r] += p;
        P[(quad * 4 + r) * 72 + ni * 16 + lrow] = (short)f2bf(p);
      }
    }

    bf16x8 pf[2];
#pragma unroll
    for (int c = 0; c < 2; c++) pf[c] = *(const bf16x8*)(&P[lrow * 72 + c * 32 + quad * 8]);
#pragma unroll
    for (int d = 0; d < 8; d++)
#pragma unroll
      for (int c = 0; c < 2; c++) {
        bf16x8 vf = *(const bf16x8*)(&VTs[(d * 16 + lrow) * 72 + c * 32 + quad * 8]);
        acc[d] = __builtin_amdgcn_mfma_f32_16x16x32_bf16(pf[c], vf, acc[d], 0, 0, 0);
      }
  }

  float inv_l[4];
#pragma unroll
  for (int r = 0; r < 4; r++) {
    float l = lsum[r];
#pragma unroll
    for (int off = 1; off < 16; off <<= 1) l += __shfl_xor(l, off, 16);
    inv_l[r] = 1.f / l;
  }
#pragma unroll
  for (int d = 0; d < 8; d++)
#pragma unroll
    for (int r = 0; r < 4; r++) {
      const int row = q0 + quad * 4 + r;
      ctx[(size_t)row * HID + h * HDIM + d * 16 + lrow] = f2bf(acc[d][r] * inv_l[r]);
    }
}

extern "C" void kernel_launch(void* const* d_in, const int* in_sizes, int n_in,
                              void* d_out, int out_size, void* d_ws, size_t ws_size,
                              hipStream_t stream) {
  const float* hidden = (const float*)d_in[0];
  const float* lnw    = (const float*)d_in[1];
  const float* lnb    = (const float*)d_in[2];
  const float* qkvw   = (const float*)d_in[3];
  const float* qkvb   = (const float*)d_in[4];
  const float* projw  = (const float*)d_in[5];
  const float* projb  = (const float*)d_in[6];
  float* out = (float*)d_out;

  // ws: [0,8M) ln_x / ctx ; [8M,24M) mixed Q|K (ld 4096) ; [24M,32M) V^T global
  //     [32M,56M) qkvw bf16 ; [56M,64M) projw bf16  (big path only)
  char* ws = (char*)d_ws;
  ushort_t* ln_x    = (ushort_t*)ws;
  ushort_t* mixedQK = (ushort_t*)(ws + ((size_t)8 << 20));
  ushort_t* vtg     = (ushort_t*)(ws + ((size_t)24 << 20));
  ushort_t* qkvw_bf = (ushort_t*)(ws + ((size_t)32 << 20));
  ushort_t* projw_bf= (ushort_t*)(ws + ((size_t)56 << 20));
  ushort_t* ctxb    = ln_x;
  const bool big = ws_size >= ((size_t)64 << 20);

  ln_kernel<<<S_LEN, 256, 0, stream>>>(hidden, lnw, lnb, ln_x);
  if (big) {
    cvt_f32_bf16<<<6144, 256, 0, stream>>>(qkvw, qkvw_bf, 3 * HID * HID / 8);
    cvt_f32_bf16<<<2048, 256, 0, stream>>>(projw, projw_bf, HID * HID / 8);
    gemm_lds<true, ushort_t><<<dim3(16, 48), 256, 0, stream>>>(
        ln_x, qkvw_bf, qkvb, mixedQK, vtg, S_LEN, 3 * HID, HID, LDQK);
  } else {
    gemm_bt<true, ushort_t, float><<<dim3(16, 48), 256, 0, stream>>>(
        ln_x, qkvw, qkvb, mixedQK, vtg, S_LEN, 3 * HID, HID, LDQK);
  }
  // LPT counter lives in d_out[0]; proj GEMM fully overwrites d_out afterwards
  hipMemsetAsync(d_out, 0, 4, stream);
  attn_kernel<<<512, 256, 0, stream>>>(mixedQK, vtg, ctxb, (int*)d_out);
  if (big) {
    gemm_lds<false, float><<<dim3(16, 16), 256, 0, stream>>>(
        ctxb, projw_bf, projb, out, nullptr, S_LEN, HID, HID, HID);
  } else {
    gemm_bt<false, float, float><<<dim3(16, 16), 256, 0, stream>>>(
        ctxb, projw, projb, out, nullptr, S_LEN, HID, HID, HID);
  }
}

// Round 5
// 389.595 us; speedup vs baseline: 1.0272x; 1.0272x over previous
//
#include <hip/hip_runtime.h>
#include <stdint.h>

#define S_LEN 2048
#define HID   2048
#define NHEAD 16
#define HDIM  128
#define LDQK  4096   // row stride of mixed Q|K buffer

typedef unsigned short ushort_t;
using bf16x8 = __attribute__((ext_vector_type(8))) short;
using f32x4  = __attribute__((ext_vector_type(4))) float;

__device__ __forceinline__ float bf2f(ushort_t u) {
  union { uint32_t i; float f; } v; v.i = ((uint32_t)u) << 16; return v.f;
}
__device__ __forceinline__ ushort_t f2bf(float f) {
  union { float f; uint32_t i; } v; v.f = f;
  uint32_t r = v.i + 0x7fffu + ((v.i >> 16) & 1u);
  return (ushort_t)(r >> 16);
}
__device__ __forceinline__ void store_val(ushort_t* C, size_t idx, float v) { C[idx] = f2bf(v); }
__device__ __forceinline__ void store_val(float* C, size_t idx, float v) { C[idx] = v; }

__device__ __forceinline__ bf16x8 load8(const ushort_t* p) { return *(const bf16x8*)p; }
__device__ __forceinline__ bf16x8 load8(const float* p) {
  float4 a = *(const float4*)p, b = *(const float4*)(p + 4);
  ushort_t o[8] = { f2bf(a.x), f2bf(a.y), f2bf(a.z), f2bf(a.w),
                    f2bf(b.x), f2bf(b.y), f2bf(b.z), f2bf(b.w) };
  return *(const bf16x8*)o;
}

// async global->LDS, 16B per lane, LDS dest = wave-uniform base + lane*16
__device__ __forceinline__ void gl_lds16(const ushort_t* g, short* l) {
  __builtin_amdgcn_global_load_lds((const __attribute__((address_space(1))) void*)g,
                                   (__attribute__((address_space(3))) void*)l, 16, 0, 0);
}

// ---------------- fp32 -> bf16 conversion ----------------
__global__ __launch_bounds__(256) void cvt_f32_bf16(const float* __restrict__ src,
                                                    ushort_t* __restrict__ dst, int n8) {
  int i = blockIdx.x * 256 + threadIdx.x;
  if (i >= n8) return;
  float4 a = ((const float4*)src)[i * 2], b = ((const float4*)src)[i * 2 + 1];
  ushort_t o[8] = { f2bf(a.x), f2bf(a.y), f2bf(a.z), f2bf(a.w),
                    f2bf(b.x), f2bf(b.y), f2bf(b.z), f2bf(b.w) };
  ((uint4*)dst)[i] = *(const uint4*)o;
}

// ---------------- LayerNorm: fp32 in, bf16 out ----------------
__global__ __launch_bounds__(256) void ln_kernel(const float* __restrict__ x,
                                                 const float* __restrict__ w,
                                                 const float* __restrict__ b,
                                                 ushort_t* __restrict__ y) {
  const int row = blockIdx.x;
  const int t = threadIdx.x;
  const float4* xr = (const float4*)(x + (size_t)row * HID);
  float4 v0 = xr[t], v1 = xr[t + 256];
  float s  = v0.x + v0.y + v0.z + v0.w + v1.x + v1.y + v1.z + v1.w;
  float ss = v0.x*v0.x + v0.y*v0.y + v0.z*v0.z + v0.w*v0.w
           + v1.x*v1.x + v1.y*v1.y + v1.z*v1.z + v1.w*v1.w;
#pragma unroll
  for (int off = 32; off > 0; off >>= 1) { s += __shfl_xor(s, off, 64); ss += __shfl_xor(ss, off, 64); }
  __shared__ float red[8];
  const int wv = t >> 6;
  if ((t & 63) == 0) { red[wv * 2] = s; red[wv * 2 + 1] = ss; }
  __syncthreads();
  s  = red[0] + red[2] + red[4] + red[6];
  ss = red[1] + red[3] + red[5] + red[7];
  const float mu   = s * (1.f / HID);
  const float var  = ss * (1.f / HID) - mu * mu;
  const float rstd = rsqrtf(var + 1e-5f);
  const float4* wr = (const float4*)w;
  const float4* br = (const float4*)b;
  float4 w0 = wr[t], w1 = wr[t + 256];
  float4 b0 = br[t], b1 = br[t + 256];
  ushort_t* yr = y + (size_t)row * HID;
  ushort_t o0[4] = { f2bf((v0.x - mu) * rstd * w0.x + b0.x), f2bf((v0.y - mu) * rstd * w0.y + b0.y),
                     f2bf((v0.z - mu) * rstd * w0.z + b0.z), f2bf((v0.w - mu) * rstd * w0.w + b0.w) };
  ushort_t o1[4] = { f2bf((v1.x - mu) * rstd * w1.x + b1.x), f2bf((v1.y - mu) * rstd * w1.y + b1.y),
                     f2bf((v1.z - mu) * rstd * w1.z + b1.z), f2bf((v1.w - mu) * rstd * w1.w + b1.w) };
  *(uint2*)(&yr[4 * t])         = *(const uint2*)o0;
  *(uint2*)(&yr[4 * (t + 256)]) = *(const uint2*)o1;
}

// ---- m97-style GEMM (bf16 A and B): global_load_lds staging, unpadded 128x32 tiles ----
template <bool SPLIT, typename OUT_T>
__global__ __launch_bounds__(256, 3) void gemm_lds(const ushort_t* __restrict__ A,
                                                   const ushort_t* __restrict__ B,
                                                   const float* __restrict__ bias,
                                                   OUT_T* __restrict__ C,
                                                   ushort_t* __restrict__ VTg,
                                                   int M, int N, int K, int ldc) {
  __shared__ __align__(16) short As[128 * 32];
  __shared__ __align__(16) short Bs[128 * 32];
  const int mb = blockIdx.x * 128, nb = blockIdx.y * 128;
  const int t = threadIdx.x, wave = t >> 6, lane = t & 63;
  const int wm = (wave >> 1) * 64, wn = (wave & 1) * 64;
  const int lrow = lane & 15, quad = lane >> 4;
  const int srow = lane >> 2, scol = (lane & 3) * 8;  // staging: 4 lanes per 32-elem row
  const f32x4 vzero = {0.f, 0.f, 0.f, 0.f};

  f32x4 acc[4][4];
#pragma unroll
  for (int i = 0; i < 4; i++)
#pragma unroll
    for (int j = 0; j < 4; j++) acc[i][j] = vzero;

  for (int k0 = 0; k0 < K; k0 += 32) {
    __syncthreads();
#pragma unroll
    for (int kb = 0; kb < 2; kb++) {
      const int c = wave * 2 + kb;          // chunk 0..7, 16 rows each
      const int row = c * 16 + srow;
      gl_lds16(&A[(size_t)(mb + row) * K + k0 + scol], &As[c * 512]);
      gl_lds16(&B[(size_t)(nb + row) * K + k0 + scol], &Bs[c * 512]);
    }
    __syncthreads();
    bf16x8 af[4], bfg[4];
#pragma unroll
    for (int mi = 0; mi < 4; mi++) af[mi] = *(const bf16x8*)(&As[(wm + mi * 16 + lrow) * 32 + quad * 8]);
#pragma unroll
    for (int ni = 0; ni < 4; ni++) bfg[ni] = *(const bf16x8*)(&Bs[(wn + ni * 16 + lrow) * 32 + quad * 8]);
#pragma unroll
    for (int mi = 0; mi < 4; mi++)
#pragma unroll
      for (int ni = 0; ni < 4; ni++)
        acc[mi][ni] = __builtin_amdgcn_mfma_f32_16x16x32_bf16(af[mi], bfg[ni], acc[mi][ni], 0, 0, 0);
  }

#pragma unroll
  for (int mi = 0; mi < 4; mi++)
#pragma unroll
    for (int ni = 0; ni < 4; ni++) {
      const int col = nb + wn + ni * 16 + lrow;
      const float bv = bias[col];
      const int row0 = mb + wm + mi * 16 + quad * 4;
      if (SPLIT && col >= 4096) {
        ushort_t o4[4];
#pragma unroll
        for (int r = 0; r < 4; r++) o4[r] = f2bf(acc[mi][ni][r] + bv);
        *(uint2*)(&VTg[(size_t)(col - 4096) * S_LEN + row0]) = *(const uint2*)o4;
      } else {
#pragma unroll
        for (int r = 0; r < 4; r++)
          store_val(C, (size_t)(row0 + r) * ldc + col, acc[mi][ni][r] + bv);
      }
    }
}

// ---- fallback GEMM (fp32 B converted in-loop), for small-ws path ----
template <bool SPLIT, typename OUT_T, typename BT>
__global__ __launch_bounds__(256, 3) void gemm_bt(const ushort_t* __restrict__ A,
                                                  const BT* __restrict__ B,
                                                  const float* __restrict__ bias,
                                                  OUT_T* __restrict__ C,
                                                  ushort_t* __restrict__ VTg,
                                                  int M, int N, int K, int ldc) {
  __shared__ __align__(16) short As[128 * 40];
  __shared__ __align__(16) short Bs[128 * 40];
  const int mb = blockIdx.x * 128, nb = blockIdx.y * 128;
  const int t = threadIdx.x, wave = t >> 6, lane = t & 63;
  const int wm = (wave >> 1) * 64, wn = (wave & 1) * 64;
  const int lrow = lane & 15, quad = lane >> 4;
  const f32x4 vzero = {0.f, 0.f, 0.f, 0.f};
  f32x4 acc[4][4];
#pragma unroll
  for (int i = 0; i < 4; i++)
#pragma unroll
    for (int j = 0; j < 4; j++) acc[i][j] = vzero;
  for (int k0 = 0; k0 < K; k0 += 32) {
    __syncthreads();
#pragma unroll
    for (int i = 0; i < 2; i++) {
      int c = t + 256 * i;
      int r = c >> 2, kc = (c & 3) * 8;
      *(bf16x8*)(&As[r * 40 + kc]) = load8(&A[(size_t)(mb + r) * K + k0 + kc]);
      *(bf16x8*)(&Bs[r * 40 + kc]) = load8(&B[(size_t)(nb + r) * K + k0 + kc]);
    }
    __syncthreads();
    bf16x8 af[4], bfg[4];
#pragma unroll
    for (int mi = 0; mi < 4; mi++) af[mi] = *(const bf16x8*)(&As[(wm + mi * 16 + lrow) * 40 + quad * 8]);
#pragma unroll
    for (int ni = 0; ni < 4; ni++) bfg[ni] = *(const bf16x8*)(&Bs[(wn + ni * 16 + lrow) * 40 + quad * 8]);
#pragma unroll
    for (int mi = 0; mi < 4; mi++)
#pragma unroll
      for (int ni = 0; ni < 4; ni++)
        acc[mi][ni] = __builtin_amdgcn_mfma_f32_16x16x32_bf16(af[mi], bfg[ni], acc[mi][ni], 0, 0, 0);
  }
#pragma unroll
  for (int mi = 0; mi < 4; mi++)
#pragma unroll
    for (int ni = 0; ni < 4; ni++) {
      const int col = nb + wn + ni * 16 + lrow;
      const float bv = bias[col];
      const int row0 = mb + wm + mi * 16 + quad * 4;
      if (SPLIT && col >= 4096) {
        ushort_t o4[4];
#pragma unroll
        for (int r = 0; r < 4; r++) o4[r] = f2bf(acc[mi][ni][r] + bv);
        *(uint2*)(&VTg[(size_t)(col - 4096) * S_LEN + row0]) = *(const uint2*)o4;
      } else {
#pragma unroll
        for (int r = 0; r < 4; r++)
          store_val(C, (size_t)(row0 + r) * ldc + col, acc[mi][ni][r] + bv);
      }
    }
}

// ---------------- Causal flash attention: LPT work-stealing + register prefetch ----------------
// __launch_bounds__(256, 3): LDS (45.5KB) caps at 3 blocks/CU anyway; this raises the VGPR
// cap to ~170 so the 32-VGPR cross-tile prefetch does NOT spill to scratch (round-4 lesson:
// WRITE_SIZE 8MB -> 206MB from spills at the default VGPR target).
__global__ __launch_bounds__(256, 3) void attn_kernel(const ushort_t* __restrict__ mixedQK,
                                                      const ushort_t* __restrict__ vtg,
                                                      ushort_t* __restrict__ ctx,
                                                      int* __restrict__ ctr) {
  __shared__ int sItem;
  const int t = threadIdx.x;
  if (t == 0) sItem = atomicAdd(ctr, 1);   // device-scope; LPT: biggest jobs pop first
  __syncthreads();
  const int item = sItem;
  const int h = item & 15;
  const int qblk = 31 - (item >> 4);       // qblk 31 (32 tiles) first, 0 (1 tile) last

  const int wave = t >> 6, lane = t & 63;
  const int lrow = lane & 15, quad = lane >> 4;
  const int q0 = qblk * 64 + wave * 16;
  const float scale = 0.08838834764831845f;  // 1/sqrt(128)
  const float SHIFT = 8.0f;                  // fixed softmax shift

  __shared__ __align__(16) short Ks[64 * 136];   // [64 kv][128+8]
  __shared__ __align__(16) short VTs[128 * 72];  // [128 d][64+8]
  __shared__ __align__(16) short Ps[4][16 * 72]; // per-wave P (wave-local, no barrier)

  bf16x8 qf[4];
  {
    const ushort_t* Qb = mixedQK + (size_t)(q0 + lrow) * LDQK + h * HDIM;
#pragma unroll
    for (int c = 0; c < 4; c++) qf[c] = *(const bf16x8*)(Qb + c * 32 + quad * 8);
  }

  const f32x4 vzero = {0.f, 0.f, 0.f, 0.f};
  float lsum[4] = {0.f, 0.f, 0.f, 0.f};
  f32x4 acc[8];
#pragma unroll
  for (int d = 0; d < 8; d++) acc[d] = vzero;

  uint4 kreg[4], vreg[4];
  // prefetch tile 0
#pragma unroll
  for (int i = 0; i < 4; i++) {
    int c = t + 256 * i; int r = c >> 4, kc = (c & 15) * 8;
    kreg[i] = *(const uint4*)(&mixedQK[(size_t)r * LDQK + 2048 + h * HDIM + kc]);
  }
#pragma unroll
  for (int i = 0; i < 4; i++) {
    int c = t + 256 * i; int dd = c >> 3, j8 = (c & 7) * 8;
    vreg[i] = *(const uint4*)(&vtg[(size_t)(h * HDIM + dd) * S_LEN + j8]);
  }

  const int ntiles = qblk + 1;
  for (int tk = 0; tk < ntiles; ++tk) {
    const int kv0 = tk * 64;
    __syncthreads();   // prior tile's LDS reads complete
#pragma unroll
    for (int i = 0; i < 4; i++) {
      int c = t + 256 * i; int r = c >> 4, kc = (c & 15) * 8;
      *(uint4*)(&Ks[r * 136 + kc]) = kreg[i];
    }
#pragma unroll
    for (int i = 0; i < 4; i++) {
      int c = t + 256 * i; int dd = c >> 3, j8 = (c & 7) * 8;
      *(uint4*)(&VTs[dd * 72 + j8]) = vreg[i];
    }
    __syncthreads();   // staging visible

    // issue next tile's global loads now — latency hides behind compute below
    if (tk + 1 < ntiles) {
      const int nv0 = kv0 + 64;
#pragma unroll
      for (int i = 0; i < 4; i++) {
        int c = t + 256 * i; int r = c >> 4, kc = (c & 15) * 8;
        kreg[i] = *(const uint4*)(&mixedQK[(size_t)(nv0 + r) * LDQK + 2048 + h * HDIM + kc]);
      }
#pragma unroll
      for (int i = 0; i < 4; i++) {
        int c = t + 256 * i; int dd = c >> 3, j8 = (c & 7) * 8;
        vreg[i] = *(const uint4*)(&vtg[(size_t)(h * HDIM + dd) * S_LEN + nv0 + j8]);
      }
    }

    // S = Q K^T
    f32x4 sc[4];
#pragma unroll
    for (int ni = 0; ni < 4; ni++) sc[ni] = vzero;
#pragma unroll
    for (int ni = 0; ni < 4; ni++)
#pragma unroll
      for (int c = 0; c < 4; c++) {
        bf16x8 kf = *(const bf16x8*)(&Ks[(ni * 16 + lrow) * 136 + c * 32 + quad * 8]);
        sc[ni] = __builtin_amdgcn_mfma_f32_16x16x32_bf16(qf[c], kf, sc[ni], 0, 0, 0);
      }

    // fixed-shift softmax -> bf16 P (per-wave LDS; wave-internal lgkm ordering suffices)
    short* P = &Ps[wave][0];
#pragma unroll
    for (int r = 0; r < 4; r++) {
      const int row = q0 + quad * 4 + r;
#pragma unroll
      for (int ni = 0; ni < 4; ni++) {
        const int col = kv0 + ni * 16 + lrow;
        float p = (col > row) ? 0.f : __expf(sc[ni][r] * scale - SHIFT);
        lsum[r] += p;
        P[(quad * 4 + r) * 72 + ni * 16 + lrow] = (short)f2bf(p);
      }
    }

    bf16x8 pf[2];
#pragma unroll
    for (int c = 0; c < 2; c++) pf[c] = *(const bf16x8*)(&P[lrow * 72 + c * 32 + quad * 8]);
#pragma unroll
    for (int d = 0; d < 8; d++)
#pragma unroll
      for (int c = 0; c < 2; c++) {
        bf16x8 vf = *(const bf16x8*)(&VTs[(d * 16 + lrow) * 72 + c * 32 + quad * 8]);
        acc[d] = __builtin_amdgcn_mfma_f32_16x16x32_bf16(pf[c], vf, acc[d], 0, 0, 0);
      }
  }

  float inv_l[4];
#pragma unroll
  for (int r = 0; r < 4; r++) {
    float l = lsum[r];
#pragma unroll
    for (int off = 1; off < 16; off <<= 1) l += __shfl_xor(l, off, 16);
    inv_l[r] = 1.f / l;
  }
#pragma unroll
  for (int d = 0; d < 8; d++)
#pragma unroll
    for (int r = 0; r < 4; r++) {
      const int row = q0 + quad * 4 + r;
      ctx[(size_t)row * HID + h * HDIM + d * 16 + lrow] = f2bf(acc[d][r] * inv_l[r]);
    }
}

extern "C" void kernel_launch(void* const* d_in, const int* in_sizes, int n_in,
                              void* d_out, int out_size, void* d_ws, size_t ws_size,
                              hipStream_t stream) {
  const float* hidden = (const float*)d_in[0];
  const float* lnw    = (const float*)d_in[1];
  const float* lnb    = (const float*)d_in[2];
  const float* qkvw   = (const float*)d_in[3];
  const float* qkvb   = (const float*)d_in[4];
  const float* projw  = (const float*)d_in[5];
  const float* projb  = (const float*)d_in[6];
  float* out = (float*)d_out;

  // ws: [0,8M) ln_x / ctx ; [8M,24M) mixed Q|K (ld 4096) ; [24M,32M) V^T global
  //     [32M,56M) qkvw bf16 ; [56M,64M) projw bf16  (big path only)
  char* ws = (char*)d_ws;
  ushort_t* ln_x    = (ushort_t*)ws;
  ushort_t* mixedQK = (ushort_t*)(ws + ((size_t)8 << 20));
  ushort_t* vtg     = (ushort_t*)(ws + ((size_t)24 << 20));
  ushort_t* qkvw_bf = (ushort_t*)(ws + ((size_t)32 << 20));
  ushort_t* projw_bf= (ushort_t*)(ws + ((size_t)56 << 20));
  ushort_t* ctxb    = ln_x;
  const bool big = ws_size >= ((size_t)64 << 20);

  ln_kernel<<<S_LEN, 256, 0, stream>>>(hidden, lnw, lnb, ln_x);
  if (big) {
    cvt_f32_bf16<<<6144, 256, 0, stream>>>(qkvw, qkvw_bf, 3 * HID * HID / 8);
    cvt_f32_bf16<<<2048, 256, 0, stream>>>(projw, projw_bf, HID * HID / 8);
    gemm_lds<true, ushort_t><<<dim3(16, 48), 256, 0, stream>>>(
        ln_x, qkvw_bf, qkvb, mixedQK, vtg, S_LEN, 3 * HID, HID, LDQK);
  } else {
    gemm_bt<true, ushort_t, float><<<dim3(16, 48), 256, 0, stream>>>(
        ln_x, qkvw, qkvb, mixedQK, vtg, S_LEN, 3 * HID, HID, LDQK);
  }
  // LPT counter lives in d_out[0]; proj GEMM fully overwrites d_out afterwards
  hipMemsetAsync(d_out, 0, 4, stream);
  attn_kernel<<<512, 256, 0, stream>>>(mixedQK, vtg, ctxb, (int*)d_out);
  if (big) {
    gemm_lds<false, float><<<dim3(16, 16), 256, 0, stream>>>(
        ctxb, projw_bf, projb, out, nullptr, S_LEN, HID, HID, HID);
  } else {
    gemm_bt<false, float, float><<<dim3(16, 16), 256, 0, stream>>>(
        ctxb, projw, projb, out, nullptr, S_LEN, HID, HID, HID);
  }
}

// Round 6
// 277.488 us; speedup vs baseline: 1.4421x; 1.4040x over previous
//
#include <hip/hip_runtime.h>
#include <stdint.h>

#define S_LEN 2048
#define HID   2048
#define NHEAD 16
#define HDIM  128
#define LDQK  4096   // row stride of mixed Q|K buffer

typedef unsigned short ushort_t;
using bf16x8 = __attribute__((ext_vector_type(8))) short;
using f32x4  = __attribute__((ext_vector_type(4))) float;

__device__ __forceinline__ float bf2f(ushort_t u) {
  union { uint32_t i; float f; } v; v.i = ((uint32_t)u) << 16; return v.f;
}
__device__ __forceinline__ ushort_t f2bf(float f) {
  union { float f; uint32_t i; } v; v.f = f;
  uint32_t r = v.i + 0x7fffu + ((v.i >> 16) & 1u);
  return (ushort_t)(r >> 16);
}
__device__ __forceinline__ void store_val(ushort_t* C, size_t idx, float v) { C[idx] = f2bf(v); }
__device__ __forceinline__ void store_val(float* C, size_t idx, float v) { C[idx] = v; }

__device__ __forceinline__ bf16x8 load8(const ushort_t* p) { return *(const bf16x8*)p; }
__device__ __forceinline__ bf16x8 load8(const float* p) {
  float4 a = *(const float4*)p, b = *(const float4*)(p + 4);
  ushort_t o[8] = { f2bf(a.x), f2bf(a.y), f2bf(a.z), f2bf(a.w),
                    f2bf(b.x), f2bf(b.y), f2bf(b.z), f2bf(b.w) };
  return *(const bf16x8*)o;
}

// async global->LDS, 16B per lane; LDS dest = wave-uniform base + lane*16 (HW-appended)
__device__ __forceinline__ void gl_lds16(const ushort_t* g, short* l) {
  __builtin_amdgcn_global_load_lds((const __attribute__((address_space(1))) void*)g,
                                   (__attribute__((address_space(3))) void*)l, 16, 0, 0);
}

// ---------------- fp32 -> bf16 conversion ----------------
__global__ __launch_bounds__(256) void cvt_f32_bf16(const float* __restrict__ src,
                                                    ushort_t* __restrict__ dst, int n8) {
  int i = blockIdx.x * 256 + threadIdx.x;
  if (i >= n8) return;
  float4 a = ((const float4*)src)[i * 2], b = ((const float4*)src)[i * 2 + 1];
  ushort_t o[8] = { f2bf(a.x), f2bf(a.y), f2bf(a.z), f2bf(a.w),
                    f2bf(b.x), f2bf(b.y), f2bf(b.z), f2bf(b.w) };
  ((uint4*)dst)[i] = *(const uint4*)o;
}

// ---------------- LayerNorm: fp32 in, bf16 out ----------------
__global__ __launch_bounds__(256) void ln_kernel(const float* __restrict__ x,
                                                 const float* __restrict__ w,
                                                 const float* __restrict__ b,
                                                 ushort_t* __restrict__ y) {
  const int row = blockIdx.x;
  const int t = threadIdx.x;
  const float4* xr = (const float4*)(x + (size_t)row * HID);
  float4 v0 = xr[t], v1 = xr[t + 256];
  float s  = v0.x + v0.y + v0.z + v0.w + v1.x + v1.y + v1.z + v1.w;
  float ss = v0.x*v0.x + v0.y*v0.y + v0.z*v0.z + v0.w*v0.w
           + v1.x*v1.x + v1.y*v1.y + v1.z*v1.z + v1.w*v1.w;
#pragma unroll
  for (int off = 32; off > 0; off >>= 1) { s += __shfl_xor(s, off, 64); ss += __shfl_xor(ss, off, 64); }
  __shared__ float red[8];
  const int wv = t >> 6;
  if ((t & 63) == 0) { red[wv * 2] = s; red[wv * 2 + 1] = ss; }
  __syncthreads();
  s  = red[0] + red[2] + red[4] + red[6];
  ss = red[1] + red[3] + red[5] + red[7];
  const float mu   = s * (1.f / HID);
  const float var  = ss * (1.f / HID) - mu * mu;
  const float rstd = rsqrtf(var + 1e-5f);
  const float4* wr = (const float4*)w;
  const float4* br = (const float4*)b;
  float4 w0 = wr[t], w1 = wr[t + 256];
  float4 b0 = br[t], b1 = br[t + 256];
  ushort_t* yr = y + (size_t)row * HID;
  ushort_t o0[4] = { f2bf((v0.x - mu) * rstd * w0.x + b0.x), f2bf((v0.y - mu) * rstd * w0.y + b0.y),
                     f2bf((v0.z - mu) * rstd * w0.z + b0.z), f2bf((v0.w - mu) * rstd * w0.w + b0.w) };
  ushort_t o1[4] = { f2bf((v1.x - mu) * rstd * w1.x + b1.x), f2bf((v1.y - mu) * rstd * w1.y + b1.y),
                     f2bf((v1.z - mu) * rstd * w1.z + b1.z), f2bf((v1.w - mu) * rstd * w1.w + b1.w) };
  *(uint2*)(&yr[4 * t])         = *(const uint2*)o0;
  *(uint2*)(&yr[4 * (t + 256)]) = *(const uint2*)o1;
}

// ---- m97-style GEMM (bf16 A and B): global_load_lds staging, unpadded 128x32 tiles ----
template <bool SPLIT, typename OUT_T>
__global__ __launch_bounds__(256, 3) void gemm_lds(const ushort_t* __restrict__ A,
                                                   const ushort_t* __restrict__ B,
                                                   const float* __restrict__ bias,
                                                   OUT_T* __restrict__ C,
                                                   ushort_t* __restrict__ VTg,
                                                   int M, int N, int K, int ldc) {
  __shared__ __align__(16) short As[128 * 32];
  __shared__ __align__(16) short Bs[128 * 32];
  const int mb = blockIdx.x * 128, nb = blockIdx.y * 128;
  const int t = threadIdx.x, wave = t >> 6, lane = t & 63;
  const int wm = (wave >> 1) * 64, wn = (wave & 1) * 64;
  const int lrow = lane & 15, quad = lane >> 4;
  const int srow = lane >> 2, scol = (lane & 3) * 8;
  const f32x4 vzero = {0.f, 0.f, 0.f, 0.f};

  f32x4 acc[4][4];
#pragma unroll
  for (int i = 0; i < 4; i++)
#pragma unroll
    for (int j = 0; j < 4; j++) acc[i][j] = vzero;

  for (int k0 = 0; k0 < K; k0 += 32) {
    __syncthreads();
#pragma unroll
    for (int kb = 0; kb < 2; kb++) {
      const int c = wave * 2 + kb;
      const int row = c * 16 + srow;
      gl_lds16(&A[(size_t)(mb + row) * K + k0 + scol], &As[c * 512]);
      gl_lds16(&B[(size_t)(nb + row) * K + k0 + scol], &Bs[c * 512]);
    }
    __syncthreads();
    bf16x8 af[4], bfg[4];
#pragma unroll
    for (int mi = 0; mi < 4; mi++) af[mi] = *(const bf16x8*)(&As[(wm + mi * 16 + lrow) * 32 + quad * 8]);
#pragma unroll
    for (int ni = 0; ni < 4; ni++) bfg[ni] = *(const bf16x8*)(&Bs[(wn + ni * 16 + lrow) * 32 + quad * 8]);
#pragma unroll
    for (int mi = 0; mi < 4; mi++)
#pragma unroll
      for (int ni = 0; ni < 4; ni++)
        acc[mi][ni] = __builtin_amdgcn_mfma_f32_16x16x32_bf16(af[mi], bfg[ni], acc[mi][ni], 0, 0, 0);
  }

#pragma unroll
  for (int mi = 0; mi < 4; mi++)
#pragma unroll
    for (int ni = 0; ni < 4; ni++) {
      const int col = nb + wn + ni * 16 + lrow;
      const float bv = bias[col];
      const int row0 = mb + wm + mi * 16 + quad * 4;
      if (SPLIT && col >= 4096) {
        ushort_t o4[4];
#pragma unroll
        for (int r = 0; r < 4; r++) o4[r] = f2bf(acc[mi][ni][r] + bv);
        *(uint2*)(&VTg[(size_t)(col - 4096) * S_LEN + row0]) = *(const uint2*)o4;
      } else {
#pragma unroll
        for (int r = 0; r < 4; r++)
          store_val(C, (size_t)(row0 + r) * ldc + col, acc[mi][ni][r] + bv);
      }
    }
}

// ---- fallback GEMM (fp32 B converted in-loop), small-ws path ----
template <bool SPLIT, typename OUT_T, typename BT>
__global__ __launch_bounds__(256, 3) void gemm_bt(const ushort_t* __restrict__ A,
                                                  const BT* __restrict__ B,
                                                  const float* __restrict__ bias,
                                                  OUT_T* __restrict__ C,
                                                  ushort_t* __restrict__ VTg,
                                                  int M, int N, int K, int ldc) {
  __shared__ __align__(16) short As[128 * 40];
  __shared__ __align__(16) short Bs[128 * 40];
  const int mb = blockIdx.x * 128, nb = blockIdx.y * 128;
  const int t = threadIdx.x, wave = t >> 6, lane = t & 63;
  const int wm = (wave >> 1) * 64, wn = (wave & 1) * 64;
  const int lrow = lane & 15, quad = lane >> 4;
  const f32x4 vzero = {0.f, 0.f, 0.f, 0.f};
  f32x4 acc[4][4];
#pragma unroll
  for (int i = 0; i < 4; i++)
#pragma unroll
    for (int j = 0; j < 4; j++) acc[i][j] = vzero;
  for (int k0 = 0; k0 < K; k0 += 32) {
    __syncthreads();
#pragma unroll
    for (int i = 0; i < 2; i++) {
      int c = t + 256 * i;
      int r = c >> 2, kc = (c & 3) * 8;
      *(bf16x8*)(&As[r * 40 + kc]) = load8(&A[(size_t)(mb + r) * K + k0 + kc]);
      *(bf16x8*)(&Bs[r * 40 + kc]) = load8(&B[(size_t)(nb + r) * K + k0 + kc]);
    }
    __syncthreads();
    bf16x8 af[4], bfg[4];
#pragma unroll
    for (int mi = 0; mi < 4; mi++) af[mi] = *(const bf16x8*)(&As[(wm + mi * 16 + lrow) * 40 + quad * 8]);
#pragma unroll
    for (int ni = 0; ni < 4; ni++) bfg[ni] = *(const bf16x8*)(&Bs[(wn + ni * 16 + lrow) * 40 + quad * 8]);
#pragma unroll
    for (int mi = 0; mi < 4; mi++)
#pragma unroll
      for (int ni = 0; ni < 4; ni++)
        acc[mi][ni] = __builtin_amdgcn_mfma_f32_16x16x32_bf16(af[mi], bfg[ni], acc[mi][ni], 0, 0, 0);
  }
#pragma unroll
  for (int mi = 0; mi < 4; mi++)
#pragma unroll
    for (int ni = 0; ni < 4; ni++) {
      const int col = nb + wn + ni * 16 + lrow;
      const float bv = bias[col];
      const int row0 = mb + wm + mi * 16 + quad * 4;
      if (SPLIT && col >= 4096) {
        ushort_t o4[4];
#pragma unroll
        for (int r = 0; r < 4; r++) o4[r] = f2bf(acc[mi][ni][r] + bv);
        *(uint2*)(&VTg[(size_t)(col - 4096) * S_LEN + row0]) = *(const uint2*)o4;
      } else {
#pragma unroll
        for (int r = 0; r < 4; r++)
          store_val(C, (size_t)(row0 + r) * ldc + col, acc[mi][ni][r] + bv);
      }
    }
}

// ---------------- Causal flash attention ----------------
// 256 blocks; block = (head h = b&15, pair p = b>>4) processes q-tiles {p, 31-p} sequentially
// -> constant 33 KV-tile-units per block (perfect static balance, placement-independent).
// K/V staged by async global_load_lds into double-buffered unpadded LDS; XOR column swizzle
// applied at the GLOBAL source address (global_load_lds's LDS layout is fixed lane-contiguous)
// so MFMA fragment ds_read_b128s are 2-way (= free) instead of 16-way conflicted.
__global__ __launch_bounds__(256, 2) void attn_kernel(const ushort_t* __restrict__ mixedQK,
                                                      const ushort_t* __restrict__ vtg,
                                                      ushort_t* __restrict__ ctx) {
  const int b = blockIdx.x;
  const int h = b & 15;
  const int p = b >> 4;
  const int t = threadIdx.x;
  const int wave = t >> 6, lane = t & 63;
  const int lrow = lane & 15, quad = lane >> 4;
  const float scale = 0.08838834764831845f;  // 1/sqrt(128)
  const float SHIFT = 8.0f;                  // fixed softmax shift; scores ~N(0,1)

  __shared__ __align__(16) short Ks[2][64 * 128];   // [kv][d], unpadded, XOR-swizzled cols
  __shared__ __align__(16) short VTs[2][128 * 64];  // [d][kv], unpadded, XOR-swizzled cols
  __shared__ __align__(16) short Ps[4][16 * 72];    // per-wave P, padded (VALU-written)

  // staging source permutation (XOR swizzle)
  const int krow_off = wave * 4 + (lane >> 4);         // K stage: row within 16-row chunk
  const int kgrp = (lane & 15) ^ krow_off;             // K: 16 groups of 8 shorts per row
  const int vrow_off = wave * 8 + (lane >> 3);         // V stage: row within 32-row chunk
  const int vgrp = (lane & 7) ^ (lane >> 3);           // V: 8 groups of 8 shorts per row
  const ushort_t* Kbase = mixedQK + 2048 + h * HDIM;
  const ushort_t* Vbase = vtg + (size_t)h * HDIM * S_LEN;

  const f32x4 vzero = {0.f, 0.f, 0.f, 0.f};
  int cur = 0;

  // prefetch item-A tile 0 into buf 0
#pragma unroll
  for (int i = 0; i < 4; i++)
    gl_lds16(Kbase + (size_t)(i * 16 + krow_off) * LDQK + kgrp * 8,
             &Ks[cur][(i * 256 + wave * 64) * 8]);
#pragma unroll
  for (int i = 0; i < 4; i++)
    gl_lds16(Vbase + (size_t)(i * 32 + vrow_off) * S_LEN + vgrp * 8,
             &VTs[cur][(i * 256 + wave * 64) * 8]);

  for (int item = 0; item < 2; ++item) {
    const int qblk = item ? (31 - p) : p;
    const int ntiles = qblk + 1;
    const int q0 = qblk * 64 + wave * 16;

    bf16x8 qf[4];
    {
      const ushort_t* Qb = mixedQK + (size_t)(q0 + lrow) * LDQK + h * HDIM;
#pragma unroll
      for (int c = 0; c < 4; c++) qf[c] = *(const bf16x8*)(Qb + c * 32 + quad * 8);
    }

    float lsum[4] = {0.f, 0.f, 0.f, 0.f};
    f32x4 acc[8];
#pragma unroll
    for (int d = 0; d < 8; d++) acc[d] = vzero;

    for (int tk = 0; tk < ntiles; ++tk) {
      const int kv0 = tk * 64;
      __syncthreads();  // drains this tile's prefetch (vmcnt) + prev tile's LDS reads

      // async prefetch of the NEXT tile into the other buffer (0 VGPRs, overlaps compute)
      const int nv0 = (tk + 1 < ntiles) ? (tk + 1) * 64 : (item == 0 ? 0 : -1);
      if (nv0 >= 0) {
#pragma unroll
        for (int i = 0; i < 4; i++)
          gl_lds16(Kbase + (size_t)(nv0 + i * 16 + krow_off) * LDQK + kgrp * 8,
                   &Ks[cur ^ 1][(i * 256 + wave * 64) * 8]);
#pragma unroll
        for (int i = 0; i < 4; i++)
          gl_lds16(Vbase + (size_t)(i * 32 + vrow_off) * S_LEN + nv0 + vgrp * 8,
                   &VTs[cur ^ 1][(i * 256 + wave * 64) * 8]);
      }

      const short* Kc = Ks[cur];
      const short* Vc = VTs[cur];

      // S = Q K^T (swizzled frag reads: group g=c*4+quad stored at g^lrow)
      f32x4 sc[4];
#pragma unroll
      for (int ni = 0; ni < 4; ni++) sc[ni] = vzero;
#pragma unroll
      for (int ni = 0; ni < 4; ni++)
#pragma unroll
        for (int c = 0; c < 4; c++) {
          bf16x8 kf = *(const bf16x8*)(&Kc[(((ni * 16 + lrow) << 4) + ((c * 4 + quad) ^ lrow)) * 8]);
          sc[ni] = __builtin_amdgcn_mfma_f32_16x16x32_bf16(qf[c], kf, sc[ni], 0, 0, 0);
        }

      // fixed-shift softmax -> bf16 P (per-wave LDS, no barrier needed)
      short* P = &Ps[wave][0];
#pragma unroll
      for (int r = 0; r < 4; r++) {
        const int row = q0 + quad * 4 + r;
#pragma unroll
        for (int ni = 0; ni < 4; ni++) {
          const int col = kv0 + ni * 16 + lrow;
          float pe = (col > row) ? 0.f : __expf(sc[ni][r] * scale - SHIFT);
          lsum[r] += pe;
          P[(quad * 4 + r) * 72 + ni * 16 + lrow] = (short)f2bf(pe);
        }
      }

      bf16x8 pf[2];
#pragma unroll
      for (int c = 0; c < 2; c++) pf[c] = *(const bf16x8*)(&P[lrow * 72 + c * 32 + quad * 8]);
#pragma unroll
      for (int d = 0; d < 8; d++)
#pragma unroll
        for (int c = 0; c < 2; c++) {
          bf16x8 vf = *(const bf16x8*)(&Vc[(((d * 16 + lrow) << 3) + ((c * 4 + quad) ^ (lrow & 7))) * 8]);
          acc[d] = __builtin_amdgcn_mfma_f32_16x16x32_bf16(pf[c], vf, acc[d], 0, 0, 0);
        }

      cur ^= 1;
    }

    // epilogue for this q-tile
    float inv_l[4];
#pragma unroll
    for (int r = 0; r < 4; r++) {
      float l = lsum[r];
#pragma unroll
      for (int off = 1; off < 16; off <<= 1) l += __shfl_xor(l, off, 16);
      inv_l[r] = 1.f / l;
    }
#pragma unroll
    for (int d = 0; d < 8; d++)
#pragma unroll
      for (int r = 0; r < 4; r++) {
        const int row = q0 + quad * 4 + r;
        ctx[(size_t)row * HID + h * HDIM + d * 16 + lrow] = f2bf(acc[d][r] * inv_l[r]);
      }
  }
}

extern "C" void kernel_launch(void* const* d_in, const int* in_sizes, int n_in,
                              void* d_out, int out_size, void* d_ws, size_t ws_size,
                              hipStream_t stream) {
  const float* hidden = (const float*)d_in[0];
  const float* lnw    = (const float*)d_in[1];
  const float* lnb    = (const float*)d_in[2];
  const float* qkvw   = (const float*)d_in[3];
  const float* qkvb   = (const float*)d_in[4];
  const float* projw  = (const float*)d_in[5];
  const float* projb  = (const float*)d_in[6];
  float* out = (float*)d_out;

  // ws: [0,8M) ln_x / ctx ; [8M,24M) mixed Q|K (ld 4096) ; [24M,32M) V^T global
  //     [32M,56M) qkvw bf16 ; [56M,64M) projw bf16  (big path only)
  char* ws = (char*)d_ws;
  ushort_t* ln_x    = (ushort_t*)ws;
  ushort_t* mixedQK = (ushort_t*)(ws + ((size_t)8 << 20));
  ushort_t* vtg     = (ushort_t*)(ws + ((size_t)24 << 20));
  ushort_t* qkvw_bf = (ushort_t*)(ws + ((size_t)32 << 20));
  ushort_t* projw_bf= (ushort_t*)(ws + ((size_t)56 << 20));
  ushort_t* ctxb    = ln_x;
  const bool big = ws_size >= ((size_t)64 << 20);

  ln_kernel<<<S_LEN, 256, 0, stream>>>(hidden, lnw, lnb, ln_x);
  if (big) {
    cvt_f32_bf16<<<6144, 256, 0, stream>>>(qkvw, qkvw_bf, 3 * HID * HID / 8);
    cvt_f32_bf16<<<2048, 256, 0, stream>>>(projw, projw_bf, HID * HID / 8);
    gemm_lds<true, ushort_t><<<dim3(16, 48), 256, 0, stream>>>(
        ln_x, qkvw_bf, qkvb, mixedQK, vtg, S_LEN, 3 * HID, HID, LDQK);
  } else {
    gemm_bt<true, ushort_t, float><<<dim3(16, 48), 256, 0, stream>>>(
        ln_x, qkvw, qkvb, mixedQK, vtg, S_LEN, 3 * HID, HID, LDQK);
  }
  attn_kernel<<<256, 256, 0, stream>>>(mixedQK, vtg, ctxb);
  if (big) {
    gemm_lds<false, float><<<dim3(16, 16), 256, 0, stream>>>(
        ctxb, projw_bf, projb, out, nullptr, S_LEN, HID, HID, HID);
  } else {
    gemm_bt<false, float, float><<<dim3(16, 16), 256, 0, stream>>>(
        ctxb, projw, projb, out, nullptr, S_LEN, HID, HID, HID);
  }
}

// Round 7
// 273.728 us; speedup vs baseline: 1.4620x; 1.0137x over previous
//
#include <hip/hip_runtime.h>
#include <stdint.h>

#define S_LEN 2048
#define HID   2048
#define NHEAD 16
#define HDIM  128
#define LDQK  4096   // row stride of mixed Q|K buffer

typedef unsigned short ushort_t;
using bf16x8 = __attribute__((ext_vector_type(8))) short;
using f32x4  = __attribute__((ext_vector_type(4))) float;

__device__ __forceinline__ float bf2f(ushort_t u) {
  union { uint32_t i; float f; } v; v.i = ((uint32_t)u) << 16; return v.f;
}
__device__ __forceinline__ ushort_t f2bf(float f) {
  union { float f; uint32_t i; } v; v.f = f;
  uint32_t r = v.i + 0x7fffu + ((v.i >> 16) & 1u);
  return (ushort_t)(r >> 16);
}
__device__ __forceinline__ void store_val(ushort_t* C, size_t idx, float v) { C[idx] = f2bf(v); }
__device__ __forceinline__ void store_val(float* C, size_t idx, float v) { C[idx] = v; }

__device__ __forceinline__ bf16x8 load8(const ushort_t* p) { return *(const bf16x8*)p; }
__device__ __forceinline__ bf16x8 load8(const float* p) {
  float4 a = *(const float4*)p, b = *(const float4*)(p + 4);
  ushort_t o[8] = { f2bf(a.x), f2bf(a.y), f2bf(a.z), f2bf(a.w),
                    f2bf(b.x), f2bf(b.y), f2bf(b.z), f2bf(b.w) };
  return *(const bf16x8*)o;
}

// async global->LDS, 16B per lane; LDS dest = wave-uniform base + lane*16 (HW-appended)
__device__ __forceinline__ void gl_lds16(const ushort_t* g, short* l) {
  __builtin_amdgcn_global_load_lds((const __attribute__((address_space(1))) void*)g,
                                   (__attribute__((address_space(3))) void*)l, 16, 0, 0);
}

// ---------------- fp32 -> bf16 conversion ----------------
__global__ __launch_bounds__(256) void cvt_f32_bf16(const float* __restrict__ src,
                                                    ushort_t* __restrict__ dst, int n8) {
  int i = blockIdx.x * 256 + threadIdx.x;
  if (i >= n8) return;
  float4 a = ((const float4*)src)[i * 2], b = ((const float4*)src)[i * 2 + 1];
  ushort_t o[8] = { f2bf(a.x), f2bf(a.y), f2bf(a.z), f2bf(a.w),
                    f2bf(b.x), f2bf(b.y), f2bf(b.z), f2bf(b.w) };
  ((uint4*)dst)[i] = *(const uint4*)o;
}

// ---------------- LayerNorm: fp32 in, bf16 out ----------------
__global__ __launch_bounds__(256) void ln_kernel(const float* __restrict__ x,
                                                 const float* __restrict__ w,
                                                 const float* __restrict__ b,
                                                 ushort_t* __restrict__ y) {
  const int row = blockIdx.x;
  const int t = threadIdx.x;
  const float4* xr = (const float4*)(x + (size_t)row * HID);
  float4 v0 = xr[t], v1 = xr[t + 256];
  float s  = v0.x + v0.y + v0.z + v0.w + v1.x + v1.y + v1.z + v1.w;
  float ss = v0.x*v0.x + v0.y*v0.y + v0.z*v0.z + v0.w*v0.w
           + v1.x*v1.x + v1.y*v1.y + v1.z*v1.z + v1.w*v1.w;
#pragma unroll
  for (int off = 32; off > 0; off >>= 1) { s += __shfl_xor(s, off, 64); ss += __shfl_xor(ss, off, 64); }
  __shared__ float red[8];
  const int wv = t >> 6;
  if ((t & 63) == 0) { red[wv * 2] = s; red[wv * 2 + 1] = ss; }
  __syncthreads();
  s  = red[0] + red[2] + red[4] + red[6];
  ss = red[1] + red[3] + red[5] + red[7];
  const float mu   = s * (1.f / HID);
  const float var  = ss * (1.f / HID) - mu * mu;
  const float rstd = rsqrtf(var + 1e-5f);
  const float4* wr = (const float4*)w;
  const float4* br = (const float4*)b;
  float4 w0 = wr[t], w1 = wr[t + 256];
  float4 b0 = br[t], b1 = br[t + 256];
  ushort_t* yr = y + (size_t)row * HID;
  ushort_t o0[4] = { f2bf((v0.x - mu) * rstd * w0.x + b0.x), f2bf((v0.y - mu) * rstd * w0.y + b0.y),
                     f2bf((v0.z - mu) * rstd * w0.z + b0.z), f2bf((v0.w - mu) * rstd * w0.w + b0.w) };
  ushort_t o1[4] = { f2bf((v1.x - mu) * rstd * w1.x + b1.x), f2bf((v1.y - mu) * rstd * w1.y + b1.y),
                     f2bf((v1.z - mu) * rstd * w1.z + b1.z), f2bf((v1.w - mu) * rstd * w1.w + b1.w) };
  *(uint2*)(&yr[4 * t])         = *(const uint2*)o0;
  *(uint2*)(&yr[4 * (t + 256)]) = *(const uint2*)o1;
}

// ---- double-buffered m97-style GEMM: MT x 128 tile, BK=32, async LDS staging ----
// Tile k+1's global_load_lds DMA is issued right after the barrier and drains at the
// NEXT barrier, so the full compute phase hides the staging latency (critical for the
// proj GEMM at 1-2 blocks/CU where no cross-block overlap exists).
template <int MT, bool SPLIT, typename OUT_T>
__global__ __launch_bounds__(256, 3) void gemm_lds(const ushort_t* __restrict__ A,
                                                   const ushort_t* __restrict__ B,
                                                   const float* __restrict__ bias,
                                                   OUT_T* __restrict__ C,
                                                   ushort_t* __restrict__ VTg,
                                                   int M, int N, int K, int ldc) {
  constexpr int MI = MT / 32;   // m-subtiles per wave (2x2 wave grid)
  __shared__ __align__(16) short As[2][MT * 32];
  __shared__ __align__(16) short Bs[2][128 * 32];
  const int mb = blockIdx.x * MT, nb = blockIdx.y * 128;
  const int t = threadIdx.x, wave = t >> 6, lane = t & 63;
  const int wm = (wave >> 1) * (MT / 2), wn = (wave & 1) * 64;
  const int lrow = lane & 15, quad = lane >> 4;
  const int srow = lane >> 2, scol = (lane & 3) * 8;  // staging: 4 lanes per 32-elem row
  const f32x4 vzero = {0.f, 0.f, 0.f, 0.f};

  f32x4 acc[MI][4];
#pragma unroll
  for (int i = 0; i < MI; i++)
#pragma unroll
    for (int j = 0; j < 4; j++) acc[i][j] = vzero;

  // stage tile at k0 into buffer buf (async, 16-row chunks of 64 lanes x 16B)
  auto stage = [&](int k0, int buf) {
#pragma unroll
    for (int kb = 0; kb < MT / 64; kb++) {
      const int c = wave * (MT / 64) + kb;
      gl_lds16(&A[(size_t)(mb + c * 16 + srow) * K + k0 + scol], &As[buf][c * 512]);
    }
#pragma unroll
    for (int kb = 0; kb < 2; kb++) {
      const int c = wave * 2 + kb;
      gl_lds16(&B[(size_t)(nb + c * 16 + srow) * K + k0 + scol], &Bs[buf][c * 512]);
    }
  };

  stage(0, 0);
  int cur = 0;
  for (int k0 = 0; k0 < K; k0 += 32) {
    __syncthreads();                      // drains cur's DMA (vmcnt) + prev iter's ds_reads
    if (k0 + 32 < K) stage(k0 + 32, cur ^ 1);  // overlaps with compute below
    bf16x8 af[MI], bfg[4];
#pragma unroll
    for (int mi = 0; mi < MI; mi++) af[mi] = *(const bf16x8*)(&As[cur][(wm + mi * 16 + lrow) * 32 + quad * 8]);
#pragma unroll
    for (int ni = 0; ni < 4; ni++) bfg[ni] = *(const bf16x8*)(&Bs[cur][(wn + ni * 16 + lrow) * 32 + quad * 8]);
#pragma unroll
    for (int mi = 0; mi < MI; mi++)
#pragma unroll
      for (int ni = 0; ni < 4; ni++)
        acc[mi][ni] = __builtin_amdgcn_mfma_f32_16x16x32_bf16(af[mi], bfg[ni], acc[mi][ni], 0, 0, 0);
    cur ^= 1;
  }

#pragma unroll
  for (int mi = 0; mi < MI; mi++)
#pragma unroll
    for (int ni = 0; ni < 4; ni++) {
      const int col = nb + wn + ni * 16 + lrow;
      const float bv = bias[col];
      const int row0 = mb + wm + mi * 16 + quad * 4;
      if (SPLIT && col >= 4096) {
        ushort_t o4[4];
#pragma unroll
        for (int r = 0; r < 4; r++) o4[r] = f2bf(acc[mi][ni][r] + bv);
        *(uint2*)(&VTg[(size_t)(col - 4096) * S_LEN + row0]) = *(const uint2*)o4;
      } else {
#pragma unroll
        for (int r = 0; r < 4; r++)
          store_val(C, (size_t)(row0 + r) * ldc + col, acc[mi][ni][r] + bv);
      }
    }
}

// ---- fallback GEMM (fp32 B converted in-loop), small-ws path ----
template <bool SPLIT, typename OUT_T, typename BT>
__global__ __launch_bounds__(256, 3) void gemm_bt(const ushort_t* __restrict__ A,
                                                  const BT* __restrict__ B,
                                                  const float* __restrict__ bias,
                                                  OUT_T* __restrict__ C,
                                                  ushort_t* __restrict__ VTg,
                                                  int M, int N, int K, int ldc) {
  __shared__ __align__(16) short As[128 * 40];
  __shared__ __align__(16) short Bs[128 * 40];
  const int mb = blockIdx.x * 128, nb = blockIdx.y * 128;
  const int t = threadIdx.x, wave = t >> 6, lane = t & 63;
  const int wm = (wave >> 1) * 64, wn = (wave & 1) * 64;
  const int lrow = lane & 15, quad = lane >> 4;
  const f32x4 vzero = {0.f, 0.f, 0.f, 0.f};
  f32x4 acc[4][4];
#pragma unroll
  for (int i = 0; i < 4; i++)
#pragma unroll
    for (int j = 0; j < 4; j++) acc[i][j] = vzero;
  for (int k0 = 0; k0 < K; k0 += 32) {
    __syncthreads();
#pragma unroll
    for (int i = 0; i < 2; i++) {
      int c = t + 256 * i;
      int r = c >> 2, kc = (c & 3) * 8;
      *(bf16x8*)(&As[r * 40 + kc]) = load8(&A[(size_t)(mb + r) * K + k0 + kc]);
      *(bf16x8*)(&Bs[r * 40 + kc]) = load8(&B[(size_t)(nb + r) * K + k0 + kc]);
    }
    __syncthreads();
    bf16x8 af[4], bfg[4];
#pragma unroll
    for (int mi = 0; mi < 4; mi++) af[mi] = *(const bf16x8*)(&As[(wm + mi * 16 + lrow) * 40 + quad * 8]);
#pragma unroll
    for (int ni = 0; ni < 4; ni++) bfg[ni] = *(const bf16x8*)(&Bs[(wn + ni * 16 + lrow) * 40 + quad * 8]);
#pragma unroll
    for (int mi = 0; mi < 4; mi++)
#pragma unroll
      for (int ni = 0; ni < 4; ni++)
        acc[mi][ni] = __builtin_amdgcn_mfma_f32_16x16x32_bf16(af[mi], bfg[ni], acc[mi][ni], 0, 0, 0);
  }
#pragma unroll
  for (int mi = 0; mi < 4; mi++)
#pragma unroll
    for (int ni = 0; ni < 4; ni++) {
      const int col = nb + wn + ni * 16 + lrow;
      const float bv = bias[col];
      const int row0 = mb + wm + mi * 16 + quad * 4;
      if (SPLIT && col >= 4096) {
        ushort_t o4[4];
#pragma unroll
        for (int r = 0; r < 4; r++) o4[r] = f2bf(acc[mi][ni][r] + bv);
        *(uint2*)(&VTg[(size_t)(col - 4096) * S_LEN + row0]) = *(const uint2*)o4;
      } else {
#pragma unroll
        for (int r = 0; r < 4; r++)
          store_val(C, (size_t)(row0 + r) * ldc + col, acc[mi][ni][r] + bv);
      }
    }
}

// ---------------- Causal flash attention (round-6 design, unchanged) ----------------
__global__ __launch_bounds__(256, 2) void attn_kernel(const ushort_t* __restrict__ mixedQK,
                                                      const ushort_t* __restrict__ vtg,
                                                      ushort_t* __restrict__ ctx) {
  const int b = blockIdx.x;
  const int h = b & 15;
  const int p = b >> 4;
  const int t = threadIdx.x;
  const int wave = t >> 6, lane = t & 63;
  const int lrow = lane & 15, quad = lane >> 4;
  const float scale = 0.08838834764831845f;  // 1/sqrt(128)
  const float SHIFT = 8.0f;

  __shared__ __align__(16) short Ks[2][64 * 128];   // [kv][d], unpadded, XOR-swizzled cols
  __shared__ __align__(16) short VTs[2][128 * 64];  // [d][kv], unpadded, XOR-swizzled cols
  __shared__ __align__(16) short Ps[4][16 * 72];    // per-wave P, padded (VALU-written)

  const int krow_off = wave * 4 + (lane >> 4);
  const int kgrp = (lane & 15) ^ krow_off;
  const int vrow_off = wave * 8 + (lane >> 3);
  const int vgrp = (lane & 7) ^ (lane >> 3);
  const ushort_t* Kbase = mixedQK + 2048 + h * HDIM;
  const ushort_t* Vbase = vtg + (size_t)h * HDIM * S_LEN;

  const f32x4 vzero = {0.f, 0.f, 0.f, 0.f};
  int cur = 0;

#pragma unroll
  for (int i = 0; i < 4; i++)
    gl_lds16(Kbase + (size_t)(i * 16 + krow_off) * LDQK + kgrp * 8,
             &Ks[cur][(i * 256 + wave * 64) * 8]);
#pragma unroll
  for (int i = 0; i < 4; i++)
    gl_lds16(Vbase + (size_t)(i * 32 + vrow_off) * S_LEN + vgrp * 8,
             &VTs[cur][(i * 256 + wave * 64) * 8]);

  for (int item = 0; item < 2; ++item) {
    const int qblk = item ? (31 - p) : p;
    const int ntiles = qblk + 1;
    const int q0 = qblk * 64 + wave * 16;

    bf16x8 qf[4];
    {
      const ushort_t* Qb = mixedQK + (size_t)(q0 + lrow) * LDQK + h * HDIM;
#pragma unroll
      for (int c = 0; c < 4; c++) qf[c] = *(const bf16x8*)(Qb + c * 32 + quad * 8);
    }

    float lsum[4] = {0.f, 0.f, 0.f, 0.f};
    f32x4 acc[8];
#pragma unroll
    for (int d = 0; d < 8; d++) acc[d] = vzero;

    for (int tk = 0; tk < ntiles; ++tk) {
      const int kv0 = tk * 64;
      __syncthreads();

      const int nv0 = (tk + 1 < ntiles) ? (tk + 1) * 64 : (item == 0 ? 0 : -1);
      if (nv0 >= 0) {
#pragma unroll
        for (int i = 0; i < 4; i++)
          gl_lds16(Kbase + (size_t)(nv0 + i * 16 + krow_off) * LDQK + kgrp * 8,
                   &Ks[cur ^ 1][(i * 256 + wave * 64) * 8]);
#pragma unroll
        for (int i = 0; i < 4; i++)
          gl_lds16(Vbase + (size_t)(i * 32 + vrow_off) * S_LEN + nv0 + vgrp * 8,
                   &VTs[cur ^ 1][(i * 256 + wave * 64) * 8]);
      }

      const short* Kc = Ks[cur];
      const short* Vc = VTs[cur];

      f32x4 sc[4];
#pragma unroll
      for (int ni = 0; ni < 4; ni++) sc[ni] = vzero;
#pragma unroll
      for (int ni = 0; ni < 4; ni++)
#pragma unroll
        for (int c = 0; c < 4; c++) {
          bf16x8 kf = *(const bf16x8*)(&Kc[(((ni * 16 + lrow) << 4) + ((c * 4 + quad) ^ lrow)) * 8]);
          sc[ni] = __builtin_amdgcn_mfma_f32_16x16x32_bf16(qf[c], kf, sc[ni], 0, 0, 0);
        }

      short* P = &Ps[wave][0];
#pragma unroll
      for (int r = 0; r < 4; r++) {
        const int row = q0 + quad * 4 + r;
#pragma unroll
        for (int ni = 0; ni < 4; ni++) {
          const int col = kv0 + ni * 16 + lrow;
          float pe = (col > row) ? 0.f : __expf(sc[ni][r] * scale - SHIFT);
          lsum[r] += pe;
          P[(quad * 4 + r) * 72 + ni * 16 + lrow] = (short)f2bf(pe);
        }
      }

      bf16x8 pf[2];
#pragma unroll
      for (int c = 0; c < 2; c++) pf[c] = *(const bf16x8*)(&P[lrow * 72 + c * 32 + quad * 8]);
#pragma unroll
      for (int d = 0; d < 8; d++)
#pragma unroll
        for (int c = 0; c < 2; c++) {
          bf16x8 vf = *(const bf16x8*)(&Vc[(((d * 16 + lrow) << 3) + ((c * 4 + quad) ^ (lrow & 7))) * 8]);
          acc[d] = __builtin_amdgcn_mfma_f32_16x16x32_bf16(pf[c], vf, acc[d], 0, 0, 0);
        }

      cur ^= 1;
    }

    float inv_l[4];
#pragma unroll
    for (int r = 0; r < 4; r++) {
      float l = lsum[r];
#pragma unroll
      for (int off = 1; off < 16; off <<= 1) l += __shfl_xor(l, off, 16);
      inv_l[r] = 1.f / l;
    }
#pragma unroll
    for (int d = 0; d < 8; d++)
#pragma unroll
      for (int r = 0; r < 4; r++) {
        const int row = q0 + quad * 4 + r;
        ctx[(size_t)row * HID + h * HDIM + d * 16 + lrow] = f2bf(acc[d][r] * inv_l[r]);
      }
  }
}

extern "C" void kernel_launch(void* const* d_in, const int* in_sizes, int n_in,
                              void* d_out, int out_size, void* d_ws, size_t ws_size,
                              hipStream_t stream) {
  const float* hidden = (const float*)d_in[0];
  const float* lnw    = (const float*)d_in[1];
  const float* lnb    = (const float*)d_in[2];
  const float* qkvw   = (const float*)d_in[3];
  const float* qkvb   = (const float*)d_in[4];
  const float* projw  = (const float*)d_in[5];
  const float* projb  = (const float*)d_in[6];
  float* out = (float*)d_out;

  // ws: [0,8M) ln_x / ctx ; [8M,24M) mixed Q|K (ld 4096) ; [24M,32M) V^T global
  //     [32M,56M) qkvw bf16 ; [56M,64M) projw bf16  (big path only)
  char* ws = (char*)d_ws;
  ushort_t* ln_x    = (ushort_t*)ws;
  ushort_t* mixedQK = (ushort_t*)(ws + ((size_t)8 << 20));
  ushort_t* vtg     = (ushort_t*)(ws + ((size_t)24 << 20));
  ushort_t* qkvw_bf = (ushort_t*)(ws + ((size_t)32 << 20));
  ushort_t* projw_bf= (ushort_t*)(ws + ((size_t)56 << 20));
  ushort_t* ctxb    = ln_x;
  const bool big = ws_size >= ((size_t)64 << 20);

  ln_kernel<<<S_LEN, 256, 0, stream>>>(hidden, lnw, lnb, ln_x);
  if (big) {
    cvt_f32_bf16<<<6144, 256, 0, stream>>>(qkvw, qkvw_bf, 3 * HID * HID / 8);
    cvt_f32_bf16<<<2048, 256, 0, stream>>>(projw, projw_bf, HID * HID / 8);
    gemm_lds<128, true, ushort_t><<<dim3(16, 48), 256, 0, stream>>>(
        ln_x, qkvw_bf, qkvb, mixedQK, vtg, S_LEN, 3 * HID, HID, LDQK);
  } else {
    gemm_bt<true, ushort_t, float><<<dim3(16, 48), 256, 0, stream>>>(
        ln_x, qkvw, qkvb, mixedQK, vtg, S_LEN, 3 * HID, HID, LDQK);
  }
  attn_kernel<<<256, 256, 0, stream>>>(mixedQK, vtg, ctxb);
  if (big) {
    gemm_lds<64, false, float><<<dim3(32, 16), 256, 0, stream>>>(
        ctxb, projw_bf, projb, out, nullptr, S_LEN, HID, HID, HID);
  } else {
    gemm_bt<false, float, float><<<dim3(16, 16), 256, 0, stream>>>(
        ctxb, projw, projb, out, nullptr, S_LEN, HID, HID, HID);
  }
}